// Round 1
// baseline (6029.708 us; speedup 1.0000x reference)
//
#include <hip/hip_runtime.h>
#include <hip/hip_bf16.h>
#include <math.h>

#define B_ 64
#define S_ 512
#define I_ 256
#define H_ 1024
#define O_ 256

#define OUT_OFF (B_*O_)      // 16384 floats: final output
#define SLOT    (B_*H_)      // 65536 floats per hidden timestep slot

typedef __attribute__((ext_vector_type(8))) short bf16x8;  // 8 bf16 = 4 VGPRs
typedef __attribute__((ext_vector_type(4))) float f32x4;

#define LDSK 1032            // padded row stride (1024 + 8 bf16): 2-way bank alias only (free)
#define NBLK 64              // persistent blocks (one 16-row W slice each)

// ---------------- zero hidden slot 0 (h0 = 0) + hbf0 + barrier counter ----------------
__global__ void k_zero(float* __restrict__ hid, float* __restrict__ hbf0,
                       unsigned int* __restrict__ bar) {
    int i = blockIdx.x * 256 + threadIdx.x;          // 64 blocks * 256 = 16384 float4
    ((float4*)hid)[i] = make_float4(0.f, 0.f, 0.f, 0.f);
    if (i < B_ * H_ * 2 / 16)                        // 8192 float4 = 128 KB bf16 zeros
        ((float4*)hbf0)[i] = make_float4(0.f, 0.f, 0.f, 0.f);
    if (i == 0) *bar = 0u;                           // reset grid barrier each replay
}

// ---------------- convert whh fp32 -> bf16 (natural row-major layout) ----------------
__global__ void k_cvt(const float* __restrict__ src, unsigned short* __restrict__ dst) {
    int i = blockIdx.x * 256 + threadIdx.x;          // 1024 blocks: 4 elems each
    float4 v = ((const float4*)src)[i];
    ushort4 o;
    o.x = __builtin_bit_cast(unsigned short, __float2bfloat16(v.x));
    o.y = __builtin_bit_cast(unsigned short, __float2bfloat16(v.y));
    o.z = __builtin_bit_cast(unsigned short, __float2bfloat16(v.z));
    o.w = __builtin_bit_cast(unsigned short, __float2bfloat16(v.w));
    ((ushort4*)dst)[i] = o;
}

// ---------------- generic transpose src[R][C] -> dst[C][R] ----------------
__global__ void k_transpose(const float* __restrict__ src, float* __restrict__ dst,
                            int R, int C) {
    __shared__ float tile[32][33];
    int c0 = blockIdx.x * 32, r0 = blockIdx.y * 32;
    int tx = threadIdx.x, ty = threadIdx.y;          // block (32,8)
#pragma unroll
    for (int j = 0; j < 32; j += 8)
        tile[ty + j][tx] = src[(size_t)(r0 + ty + j) * C + c0 + tx];
    __syncthreads();
#pragma unroll
    for (int j = 0; j < 32; j += 8)
        dst[(size_t)(c0 + ty + j) * R + r0 + tx] = tile[tx][ty + j];
}

// ---------------- x_proj: hid[t+1][b][h] = bias[h] + sum_i x[b][t][i] * W_ih[h][i] ----------------
__global__ __launch_bounds__(256) void k_xproj(const float* __restrict__ x,
                                               const float* __restrict__ wihT, // [I_][H_]
                                               const float* __restrict__ bias,
                                               float* __restrict__ hid) {
    const int t   = blockIdx.x;
    const int hq0 = blockIdx.y * 16;                 // h-quad base (64 h per tile)
    __shared__ float xs[B_][260];                    // +4 pad
    const int tid = threadIdx.x;

#pragma unroll
    for (int it = 0; it < 16; ++it) {
        int f4 = it * 256 + tid;
        int b = f4 >> 6, iq = f4 & 63;
        float4 v = ((const float4*)x)[(size_t)b * (S_ * I_ / 4) + t * (I_ / 4) + iq];
        *(float4*)&xs[b][iq * 4] = v;
    }
    __syncthreads();

    const int hq = tid & 15;
    const int b0 = (tid >> 4) * 4;
    float4 acc[4];
    float4 bs = ((const float4*)bias)[hq0 + hq];
#pragma unroll
    for (int i = 0; i < 4; ++i) acc[i] = bs;

    const float4* w4p = (const float4*)wihT;
#pragma unroll 4
    for (int k = 0; k < I_; ++k) {
        float4 w = w4p[(size_t)k * (H_ / 4) + hq0 + hq];
#pragma unroll
        for (int i = 0; i < 4; ++i) {
            float xv = xs[b0 + i][k];
            acc[i].x += xv * w.x; acc[i].y += xv * w.y;
            acc[i].z += xv * w.z; acc[i].w += xv * w.w;
        }
    }

    float4* out4 = (float4*)hid;
#pragma unroll
    for (int i = 0; i < 4; ++i)
        out4[(size_t)(t + 1) * (SLOT / 4) + (b0 + i) * (H_ / 4) + hq0 + hq] = acc[i];
}

// ---------------- persistent recurrence: all 512 steps in one cooperative kernel ----------------
// Block 'slice' owns 16 W rows, resident in LDS for the whole sequence.
// Per step: D[16r x 64b] via 4 waves of MFMA 16x16x32 (layout identical to verified k_step),
// then tanh + fp32/bf16 stores, then a device-scope monotonic atomic grid barrier.
__global__ __launch_bounds__(256) void k_rnn(
    const unsigned short* __restrict__ whhbf,   // [H_][H_] bf16
    unsigned short* __restrict__ h0,            // ping
    unsigned short* __restrict__ h1,            // pong
    float* __restrict__ hid,
    const float* __restrict__ fcwT,             // [H_][O_]
    const float* __restrict__ fcb,
    float* __restrict__ outp,
    unsigned int* __restrict__ bar)
{
    const int slice = blockIdx.x;
    const int tid   = threadIdx.x;
    __shared__ unsigned short Ws[16 * LDSK];    // 33 KB, resident all 512 steps
    __shared__ float hl[H_];                    // 4 KB, used only by fused fc

    // stage 16 W rows (32 KB contiguous) -> padded LDS, once
    {
        const float4* src = (const float4*)(whhbf + (size_t)slice * 16 * H_);
#pragma unroll
        for (int it = 0; it < 8; ++it) {
            int c = it * 256 + tid;              // 2048 chunks of 16B (8 bf16)
            float4 v = src[c];
            int row = c >> 7, off = (c & 127) * 8;
            *(float4*)&Ws[row * LDSK + off] = v;
        }
    }
    __syncthreads();

    const int w    = tid >> 6;                   // wave = b-tile
    const int lane = tid & 63;
    const int n    = lane & 15;                  // A-row (r_local) AND B-col (b_local)
    const int quad = lane >> 4;
    const int b    = w * 16 + n;
    const int r0   = slice * 16 + quad * 4;      // C/D: row = quad*4+reg, col = n

    const unsigned short* ap = &Ws[n * LDSK + quad * 8];
    const size_t boff = (size_t)b * H_ + quad * 8;   // B-fragment offset into h buffer
    const size_t hoff = (size_t)b * H_ + r0;         // hnext store offset
    const size_t bidx = (size_t)b * (H_ / 4) + (r0 >> 2);
    unsigned short* hp[2] = {h0, h1};

    for (int t = 0; t < S_; ++t) {
        const unsigned short* bp = hp[t & 1] + boff;
        f32x4 acc0 = {0.f, 0.f, 0.f, 0.f};
        f32x4 acc1 = {0.f, 0.f, 0.f, 0.f};      // 2 chains: halve dependent MFMA latency
#pragma unroll
        for (int kk = 0; kk < 32; kk += 2) {
            bf16x8 a0 = *(const bf16x8*)(ap + kk * 32);
            bf16x8 v0 = *(const bf16x8*)(bp + kk * 32);
            acc0 = __builtin_amdgcn_mfma_f32_16x16x32_bf16(a0, v0, acc0, 0, 0, 0);
            bf16x8 a1 = *(const bf16x8*)(ap + (kk + 1) * 32);
            bf16x8 v1 = *(const bf16x8*)(bp + (kk + 1) * 32);
            acc1 = __builtin_amdgcn_mfma_f32_16x16x32_bf16(a1, v1, acc1, 0, 0, 0);
        }

        float4* slot1 = (float4*)(hid + (size_t)(t + 1) * SLOT);
        float4 xp = slot1[bidx];                 // x_proj + bias (precomputed)
        float4 hv;
        hv.x = tanhf(acc0[0] + acc1[0] + xp.x);
        hv.y = tanhf(acc0[1] + acc1[1] + xp.y);
        hv.z = tanhf(acc0[2] + acc1[2] + xp.z);
        hv.w = tanhf(acc0[3] + acc1[3] + xp.w);
        slot1[bidx] = hv;

        ushort4 hb;
        hb.x = __builtin_bit_cast(unsigned short, __float2bfloat16(hv.x));
        hb.y = __builtin_bit_cast(unsigned short, __float2bfloat16(hv.y));
        hb.z = __builtin_bit_cast(unsigned short, __float2bfloat16(hv.z));
        hb.w = __builtin_bit_cast(unsigned short, __float2bfloat16(hv.w));
        *(ushort4*)(hp[(t + 1) & 1] + hoff) = hb;

        // ---- grid barrier (monotonic counter; agent scope handles XCD L2 non-coherence)
        __syncthreads();                         // drains this block's stores (vmcnt before s_barrier)
        if (tid == 0) {
            __threadfence();                     // release: write back dirty L2 (cross-XCD visibility)
            __hip_atomic_fetch_add(bar, 1u, __ATOMIC_RELEASE, __HIP_MEMORY_SCOPE_AGENT);
            const unsigned target = (unsigned)(t + 1) * NBLK;
            while (__hip_atomic_load(bar, __ATOMIC_RELAXED, __HIP_MEMORY_SCOPE_AGENT) < target)
                __builtin_amdgcn_s_sleep(1);
            __threadfence();                     // acquire: invalidate stale L1/L2 before next reads
        }
        __syncthreads();
    }

    // ---- fused final fc: block 'slice' handles batch bb = slice (NBLK == B_)
    {
        const int bb = slice;
        ((float4*)hl)[tid] = ((const float4*)(hid + (size_t)S_ * SLOT + (size_t)bb * H_))[tid];
        __syncthreads();
        float acc = fcb[tid];
#pragma unroll 4
        for (int k = 0; k < H_; ++k)
            acc += fcwT[(size_t)k * O_ + tid] * hl[k];
        outp[bb * O_ + tid] = acc;
    }
}

// ---------------- fallback path (only if cooperative launch is rejected) ----------------
__global__ __launch_bounds__(256) void k_step(
    const unsigned short* __restrict__ whhbf,
    const unsigned short* __restrict__ hprev,
    unsigned short* __restrict__ hnext,
    float* __restrict__ hid, int t)
{
    const int slice = blockIdx.x;
    __shared__ unsigned short Ws[16 * LDSK];
    const int tid = threadIdx.x;
    {
        const float4* src = (const float4*)(whhbf + (size_t)slice * 16 * H_);
#pragma unroll
        for (int it = 0; it < 8; ++it) {
            int c = it * 256 + tid;
            float4 v = src[c];
            int row = c >> 7, off = (c & 127) * 8;
            *(float4*)&Ws[row * LDSK + off] = v;
        }
    }
    __syncthreads();

    const int w    = tid >> 6;
    const int lane = tid & 63;
    const int n    = lane & 15;
    const int quad = lane >> 4;
    const int b = w * 16 + n;
    f32x4 acc = {0.f, 0.f, 0.f, 0.f};
    const unsigned short* ap = &Ws[n * LDSK + quad * 8];
    const unsigned short* bp = hprev + (size_t)b * H_ + quad * 8;
#pragma unroll
    for (int kk = 0; kk < 32; ++kk) {
        bf16x8 af = *(const bf16x8*)(ap + kk * 32);
        bf16x8 bf = *(const bf16x8*)(bp + kk * 32);
        acc = __builtin_amdgcn_mfma_f32_16x16x32_bf16(af, bf, acc, 0, 0, 0);
    }
    const int r0 = slice * 16 + quad * 4;
    float4* slot1 = (float4*)(hid + (size_t)(t + 1) * SLOT);
    size_t idx = (size_t)b * (H_ / 4) + (r0 >> 2);
    float4 xp = slot1[idx];
    float4 hv;
    hv.x = tanhf(acc[0] + xp.x);
    hv.y = tanhf(acc[1] + xp.y);
    hv.z = tanhf(acc[2] + xp.z);
    hv.w = tanhf(acc[3] + xp.w);
    slot1[idx] = hv;
    ushort4 hb;
    hb.x = __builtin_bit_cast(unsigned short, __float2bfloat16(hv.x));
    hb.y = __builtin_bit_cast(unsigned short, __float2bfloat16(hv.y));
    hb.z = __builtin_bit_cast(unsigned short, __float2bfloat16(hv.z));
    hb.w = __builtin_bit_cast(unsigned short, __float2bfloat16(hv.w));
    *(ushort4*)(hnext + (size_t)b * H_ + r0) = hb;
}

__global__ __launch_bounds__(256) void k_fc(const float* __restrict__ fcwT,
                                            const float* __restrict__ fcb,
                                            const float* __restrict__ hid,
                                            float* __restrict__ outp) {
    const int b = blockIdx.x;
    __shared__ float hl[H_];
    const int tid = threadIdx.x;
    ((float4*)hl)[tid] = ((const float4*)(hid + (size_t)S_ * SLOT + b * H_))[tid];
    __syncthreads();
    float acc = fcb[tid];
#pragma unroll 4
    for (int k = 0; k < H_; ++k)
        acc += fcwT[(size_t)k * O_ + tid] * hl[k];
    outp[b * O_ + tid] = acc;
}

extern "C" void kernel_launch(void* const* d_in, const int* in_sizes, int n_in,
                              void* d_out, int out_size, void* d_ws, size_t ws_size,
                              hipStream_t stream) {
    const float* x    = (const float*)d_in[0];
    const float* wih  = (const float*)d_in[1];
    const float* whh  = (const float*)d_in[2];
    const float* bias = (const float*)d_in[3];
    const float* fcw  = (const float*)d_in[4];
    const float* fcb  = (const float*)d_in[5];

    float* outp = (float*)d_out;
    float* hid  = outp + OUT_OFF;

    // ws layout: whhbf 2MB | hbf0 128KB | hbf1 128KB | wihT 1MB | fcwT 1MB | bar 4B
    unsigned short* whhbf = (unsigned short*)d_ws;
    unsigned short* hbf0  = whhbf + (size_t)H_ * H_;
    unsigned short* hbf1  = hbf0 + (size_t)B_ * H_;
    float* wihT = (float*)(hbf1 + (size_t)B_ * H_);
    float* fcwT = wihT + (size_t)I_ * H_;
    unsigned int* bar = (unsigned int*)(fcwT + (size_t)H_ * O_);

    k_zero<<<SLOT / 4 / 256, 256, 0, stream>>>(hid, (float*)hbf0, bar);
    k_cvt<<<H_ * H_ / 4 / 256, 256, 0, stream>>>(whh, whhbf);
    k_transpose<<<dim3(I_ / 32, H_ / 32), dim3(32, 8), 0, stream>>>(wih, wihT, H_, I_);
    k_transpose<<<dim3(H_ / 32, O_ / 32), dim3(32, 8), 0, stream>>>(fcw, fcwT, O_, H_);

    k_xproj<<<dim3(S_, H_ / 64), 256, 0, stream>>>(x, wihT, bias, hid);

    void* args[] = {(void*)&whhbf, (void*)&hbf0, (void*)&hbf1, (void*)&hid,
                    (void*)&fcwT, (void*)&fcb, (void*)&outp, (void*)&bar};
    hipError_t e = hipLaunchCooperativeKernel((const void*)k_rnn, dim3(NBLK), dim3(256),
                                              args, 0, stream);
    if (e != hipSuccess) {
        // fallback: per-step launches (reproduces previous verified 4 ms path)
        unsigned short* hp[2] = {hbf0, hbf1};
        for (int t = 0; t < S_; ++t)
            k_step<<<64, 256, 0, stream>>>(whhbf, hp[t & 1], hp[(t + 1) & 1], hid, t);
        k_fc<<<B_, 256, 0, stream>>>(fcwT, fcb, hid, outp);
    }
}